// Round 2
// baseline (410.261 us; speedup 1.0000x reference)
//
#include <hip/hip_runtime.h>
#include <cstdint>
#include <cmath>

#define B_ 2
#define S_ 2048
#define D_ 2048
#define H_ 16
#define HD_ 128

#define NEG_SENTINEL -1.0e30f

typedef __bf16 bf16;
typedef __attribute__((ext_vector_type(4))) __bf16 bf16x4;
typedef __attribute__((ext_vector_type(8))) __bf16 bf16x8;
typedef __attribute__((ext_vector_type(4))) float f32x4;

__device__ __forceinline__ void gload_lds16(const void* g, void* l) {
  __builtin_amdgcn_global_load_lds(
      (const __attribute__((address_space(1))) unsigned int*)g,
      (__attribute__((address_space(3))) unsigned int*)l, 16, 0, 0);
}

__device__ __forceinline__ f32x4 mfma16(bf16x8 a, bf16x8 b, f32x4 c) {
  return __builtin_amdgcn_mfma_f32_16x16x32_bf16(a, b, c, 0, 0, 0);
}

__device__ __forceinline__ void wg_barrier() {
  asm volatile("" ::: "memory");
  __builtin_amdgcn_s_barrier();
  asm volatile("" ::: "memory");
}

// ---------------------------------------------------------------------------
// fp32 -> bf16 convert. One thread = 4 elements.
// ---------------------------------------------------------------------------
__global__ __launch_bounds__(256) void cvt_f32_bf16(
    const float* __restrict__ in, bf16* __restrict__ out)
{
  int i = blockIdx.x * 256 + threadIdx.x;
  f32x4 v = ((const f32x4*)in)[i];
  bf16x4 o;
#pragma unroll
  for (int j = 0; j < 4; ++j) o[j] = (bf16)v[j];
  ((bf16x4*)out)[i] = o;
}

// ---------------------------------------------------------------------------
// Legacy GEMM (kept for fallback path): 128x128 tile, BK=64. (verified R3)
// ---------------------------------------------------------------------------
#define GTM 128
#define GTN 128
#define GBK 64

template <typename OT>
__global__ __launch_bounds__(256) void gemm_xwt(
    const bf16* __restrict__ A, const bf16* __restrict__ W, OT* __restrict__ C,
    int M, int N, int K, int ldc)
{
  __shared__ bf16 sA[GTM * GBK];
  __shared__ bf16 sB[GTN * GBK];
  const int tid  = threadIdx.x;
  const int wave = tid >> 6, lane = tid & 63;
  const int quad = lane >> 4, l16 = lane & 15;
  const int tm = blockIdx.y * GTM;
  const int tn = blockIdx.x * GTN;
  const int wm = (wave >> 1) * 64, wn = (wave & 1) * 64;

  f32x4 acc[4][4];
#pragma unroll
  for (int i = 0; i < 4; ++i)
#pragma unroll
    for (int j = 0; j < 4; ++j) acc[i][j] = (f32x4)0.0f;

  for (int k0 = 0; k0 < K; k0 += GBK) {
    __syncthreads();
#pragma unroll
    for (int g = 0; g < 4; ++g) {
      int gb  = (g * 4 + wave) * 64;
      int p   = gb + lane;
      int row = p >> 3, pos = p & 7;
      int cc  = pos ^ (row & 7);
      gload_lds16(A + (size_t)(tm + row) * K + k0 + cc * 8, (char*)sA + (size_t)gb * 16);
      gload_lds16(W + (size_t)(tn + row) * K + k0 + cc * 8, (char*)sB + (size_t)gb * 16);
    }
    __syncthreads();

#pragma unroll
    for (int t = 0; t < 2; ++t) {
      bf16x8 af[4], bfr[4];
#pragma unroll
      for (int i = 0; i < 4; ++i) {
        int rowa = wm + i * 16 + l16;
        int posa = (t * 4 + quad) ^ (rowa & 7);
        af[i] = *(const bf16x8*)(sA + rowa * GBK + posa * 8);
        int rowb = wn + i * 16 + l16;
        int posb = (t * 4 + quad) ^ (rowb & 7);
        bfr[i] = *(const bf16x8*)(sB + rowb * GBK + posb * 8);
      }
#pragma unroll
      for (int i = 0; i < 4; ++i)
#pragma unroll
        for (int j = 0; j < 4; ++j)
          acc[i][j] = mfma16(af[i], bfr[j], acc[i][j]);
    }
  }

#pragma unroll
  for (int i = 0; i < 4; ++i)
#pragma unroll
    for (int r = 0; r < 4; ++r) {
      int row = tm + wm + i * 16 + quad * 4 + r;
#pragma unroll
      for (int j = 0; j < 4; ++j) {
        int col = tn + wn + j * 16 + l16;
        C[(size_t)row * ldc + col] = (OT)acc[i][j][r];
      }
    }
}

// ---------------------------------------------------------------------------
// Phase-pipelined GEMM v2 (T2+T3+T4+T5): C[m][n] = sum_k A[m][k]*W[n][k].
// BM=256 x BN=128, BK=64, 512 thr (8 waves 2Mx4N, per-wave 128x32).
// LDS 96KB: 2 dbuf x (A 32KB + B 16KB). 2 phases per K-tile, split by
// M-quadrant q so every phase's LDS-read set (union over waves) equals one
// stage unit exactly:
//   A-unit-q = rows {q*64..q*64+63} U {128+q*64..128+q*64+63}  (16KB, 2 ld)
//   B-unit   = all 128 N-rows                                  (16KB, 2 ld)
// Phase p1(t): ds_read A-u0(buf)+B(buf)->regs (b held), stage A-u1(t+1)+
//              B(t+1), bar, 16 MFMA, bar.
// Phase p2(t): ds_read A-u1(buf), stage A-u0(t+2), bar, 16 MFMA,
//              vmcnt(2) [tail: vmcnt(0)], bar.
// Ledger @ p2(t) vmcnt: outstanding = A-u0(t+1)[2] A-u1(t+1)[2] B(t+1)[2]
// A-u0(t+2)[2]; vmcnt(2) retires everything tile-(t+1) needs. Tail (t+2>=NT)
// has fewer in flight -> vmcnt(0) there. Write-safety: each stage target's
// last reader finished >=1 barrier earlier (see phase comments).
// Accumulation per element identical to gemm_xwt (k ascending, fp32 acc).
// ---------------------------------------------------------------------------
#define PTM 256
#define PTN 128
#define PBK 64
#define PBUFB 49152   // bytes per LDS buffer: A 32768 + B 16384
#define PLDSB 98304

// Stage A-unit u of K-tile kt_: rows u*64+{0..63} and 128+u*64+{0..63}.
// row0_ is a multiple of 8 -> (row&7)==(lane>>3); HW writes dst+lane*16.
#define STAGE_AU(kt_, u_) do { \
    char* dstA_ = smem + (((kt_) & 1) * PBUFB); \
    _Pragma("unroll") \
    for (int g2_ = 0; g2_ < 2; ++g2_) { \
      int row0_ = (u_) * 64 + g2_ * 128 + wave * 8; \
      int row_  = row0_ + (lane >> 3); \
      int cc_   = (lane & 7) ^ (row_ & 7); \
      gload_lds16(A + (size_t)(tm + row_) * K + (size_t)(kt_) * PBK + cc_ * 8, \
                  dstA_ + row0_ * 128); \
    } } while (0)

#define STAGE_BF(kt_) do { \
    char* dstB_ = smem + (((kt_) & 1) * PBUFB) + 32768; \
    _Pragma("unroll") \
    for (int g2_ = 0; g2_ < 2; ++g2_) { \
      int row0_ = g2_ * 64 + wave * 8; \
      int row_  = row0_ + (lane >> 3); \
      int cc_   = (lane & 7) ^ (row_ & 7); \
      gload_lds16(W + (size_t)(tn + row_) * K + (size_t)(kt_) * PBK + cc_ * 8, \
                  dstB_ + row0_ * 128); \
    } } while (0)

template <typename OT>
__global__ __launch_bounds__(512, 2) void gemm_pipe(
    const bf16* __restrict__ A, const bf16* __restrict__ W, OT* __restrict__ C,
    int M, int N, int K, int ldc, int nby)
{
  extern __shared__ char smem[];
  const int tid  = threadIdx.x;
  const int wave = tid >> 6, lane = tid & 63;
  const int quad = lane >> 4, l16 = lane & 15;

  // XCD-chunked bijective swizzle (launcher guarantees gridDim.x % 8 == 0)
  const int nwg = (int)gridDim.x;
  const int cpx = nwg >> 3;
  const int wg  = ((int)blockIdx.x & 7) * cpx + ((int)blockIdx.x >> 3);
  const int bx = wg / nby, by = wg % nby;
  const int tm = by * PTM, tn = bx * PTN;
  const int wm = (wave >> 2) * 128, wn = (wave & 3) * 32;

  const int NT = K / PBK;

  f32x4 acc[8][2];
#pragma unroll
  for (int i = 0; i < 8; ++i)
#pragma unroll
    for (int j = 0; j < 2; ++j) acc[i][j] = (f32x4)0.0f;

  // prologue: tile0 fully (6 loads) + A-u0(1) (2 loads); vmcnt(2) retires
  // exactly tile0. Matches steady-state entry condition of p1.
  STAGE_AU(0, 0);
  STAGE_AU(0, 1);
  STAGE_BF(0);
  if (NT > 1) STAGE_AU(1, 0);
  asm volatile("s_waitcnt vmcnt(2)" ::: "memory");
  wg_barrier();

#pragma unroll 1
  for (int t = 0; t < NT; ++t) {
    const bf16* sAb = (const bf16*)(smem + (t & 1) * PBUFB);
    const bf16* sBb = sAb + 16384;   // +32768 bytes
    bf16x8 a[4][2], b[2][2];

    // -------- phase 1: q_m = 0 (A rows wm..wm+63 -> A-unit0) --------
#pragma unroll
    for (int i = 0; i < 4; ++i)
#pragma unroll
      for (int t2 = 0; t2 < 2; ++t2) {
        int r  = wm + i * 16 + l16;
        int ps = (t2 * 4 + quad) ^ (r & 7);
        a[i][t2] = *(const bf16x8*)(sAb + r * 64 + ps * 8);
      }
#pragma unroll
    for (int j = 0; j < 2; ++j)
#pragma unroll
      for (int t2 = 0; t2 < 2; ++t2) {
        int r  = wn + j * 16 + l16;
        int ps = (t2 * 4 + quad) ^ (r & 7);
        b[j][t2] = *(const bf16x8*)(sBb + r * 64 + ps * 8);
      }
    // stage into buf_{t+1}: its A-u1/B last read at p2(t-1), barrier-sep'd.
    if (t + 1 < NT) { STAGE_AU(t + 1, 1); STAGE_BF(t + 1); }
    wg_barrier();
    __builtin_amdgcn_s_setprio(1);
#pragma unroll
    for (int i = 0; i < 4; ++i)
#pragma unroll
      for (int j = 0; j < 2; ++j)
#pragma unroll
        for (int t2 = 0; t2 < 2; ++t2)
          acc[i][j] = mfma16(a[i][t2], b[j][t2], acc[i][j]);
    __builtin_amdgcn_s_setprio(0);
    wg_barrier();

    // -------- phase 2: q_m = 1 (A rows wm+64..wm+127 -> A-unit1) --------
#pragma unroll
    for (int i = 0; i < 4; ++i)
#pragma unroll
      for (int t2 = 0; t2 < 2; ++t2) {
        int r  = wm + 64 + i * 16 + l16;
        int ps = (t2 * 4 + quad) ^ (r & 7);
        a[i][t2] = *(const bf16x8*)(sAb + r * 64 + ps * 8);
      }
    // stage A-u0(t+2) into buf_t: its A-u0 last read at p1(t), barrier-sep'd.
    if (t + 2 < NT) STAGE_AU(t + 2, 0);
    wg_barrier();
    __builtin_amdgcn_s_setprio(1);
#pragma unroll
    for (int i = 0; i < 4; ++i)
#pragma unroll
      for (int j = 0; j < 2; ++j)
#pragma unroll
        for (int t2 = 0; t2 < 2; ++t2)
          acc[4 + i][j] = mfma16(a[i][t2], b[j][t2], acc[4 + i][j]);
    __builtin_amdgcn_s_setprio(0);
    if (t + 2 >= NT) { asm volatile("s_waitcnt vmcnt(0)" ::: "memory"); }
    else             { asm volatile("s_waitcnt vmcnt(2)" ::: "memory"); }
    wg_barrier();
  }

#pragma unroll
  for (int i = 0; i < 8; ++i)
#pragma unroll
    for (int r = 0; r < 4; ++r) {
      int row = tm + wm + i * 16 + quad * 4 + r;
#pragma unroll
      for (int j = 0; j < 2; ++j) {
        int col = tn + wn + j * 16 + l16;
        C[(size_t)row * ldc + col] = (OT)acc[i][j][r];
      }
    }
}

// ---------------------------------------------------------------------------
// RoPE in-place; Q pre-scaled by 1/sqrt(HD)*log2(e). Row stride rs.
// ---------------------------------------------------------------------------
__global__ __launch_bounds__(256) void rope_qk(
    bf16* __restrict__ Q, bf16* __restrict__ Kk,
    const float* __restrict__ cosT, const float* __restrict__ sinT, int rs)
{
  const float kappa = 0.08838834764831845f * 1.4426950408889634f;
  int t = blockIdx.x * 256 + threadIdx.x;
  int d = t & 63;
  int h = (t >> 6) & (H_ - 1);
  int s = (t >> 10) & (S_ - 1);
  int b = t >> 21;
  size_t base = ((size_t)(b * S_ + s)) * rs + (size_t)h * HD_;
  float c1 = cosT[s * HD_ + d];
  float s1 = sinT[s * HD_ + d];
  float c2 = cosT[s * HD_ + d + 64];
  float s2 = sinT[s * HD_ + d + 64];
  {
    float x1 = (float)Q[base + d], x2 = (float)Q[base + d + 64];
    Q[base + d]      = (bf16)((x1 * c1 - x2 * s1) * kappa);
    Q[base + d + 64] = (bf16)((x2 * c2 + x1 * s2) * kappa);
  }
  {
    float x1 = (float)Kk[base + d], x2 = (float)Kk[base + d + 64];
    Kk[base + d]      = (bf16)(x1 * c1 - x2 * s1);
    Kk[base + d + 64] = (bf16)(x2 * c2 + x1 * s2);
  }
}

// ---------------------------------------------------------------------------
// V transpose: V[b][s][...] (row stride rs) -> Vt[(b*H+h)*128+d][s].
// ---------------------------------------------------------------------------
__global__ __launch_bounds__(256) void transpose_v(
    const bf16* __restrict__ V, bf16* __restrict__ Vt, int rs)
{
  __shared__ bf16 sT[64 * 72];
  const int tid = threadIdx.x;
  const int si = blockIdx.x;
  const int di = blockIdx.y;
  const int bh = blockIdx.z;
  const int b  = bh >> 4, h = bh & 15;

  const bf16* src = V + (size_t)b * S_ * rs + (size_t)h * HD_ + di * 64;
  bf16*       dst = Vt + ((size_t)bh * HD_ + di * 64) * S_ + si * 64;

#pragma unroll
  for (int half = 0; half < 2; ++half) {
    int r  = half * 32 + (tid >> 3);
    int c0 = (tid & 7) * 8;
    bf16x8 v = *(const bf16x8*)(src + (size_t)(si * 64 + r) * rs + c0);
    *(bf16x8*)(sT + r * 72 + c0) = v;
  }
  __syncthreads();
#pragma unroll
  for (int half = 0; half < 2; ++half) {
    int dr = half * 32 + (tid >> 3);
    int c0 = (tid & 7) * 8;
    bf16x8 o;
#pragma unroll
    for (int j = 0; j < 8; ++j) o[j] = sT[(c0 + j) * 72 + dr];
    *(bf16x8*)(dst + (size_t)dr * S_ + c0) = o;
  }
}

// ---------------------------------------------------------------------------
// Flash attention fwd, causal. (measured-best R8 balanced-pair structure)
// ---------------------------------------------------------------------------
#define ABK 64
#define SPS 72

__global__ __launch_bounds__(256) void attn_fwd(
    const bf16* __restrict__ Q, const bf16* __restrict__ K,
    const bf16* __restrict__ Vt, bf16* __restrict__ O, int rs)
{
  __shared__ bf16 sK[ABK * HD_];     // 16 KB
  __shared__ bf16 sVT[HD_ * ABK];    // 16 KB
  __shared__ bf16 sP[64 * SPS];      // 9 KB   (total 41 KB)

  const int tid  = threadIdx.x;
  const int wave = tid >> 6, lane = tid & 63;
  const int quad = lane >> 4, l16 = lane & 15;

  const int lin   = (int)blockIdx.x;
  const int low3  = lin & 7;
  const int rest  = lin >> 3;
  const int pairx = rest & 15;
  const int colhi = rest >> 4;
  const int col   = low3 + (colhi << 3);
  const int b = col >> 4, h = col & 15;

  const bf16* Qh  = Q + (size_t)b * S_ * rs + (size_t)h * HD_;
  const bf16* Kh  = K + (size_t)b * S_ * rs + (size_t)h * HD_;
  const bf16* Vth = Vt + ((size_t)(b * H_ + h) * HD_) * S_;
  bf16*       Oh  = O + (size_t)b * S_ * D_ + (size_t)h * HD_;

  const int wq = wave * 16;

#pragma unroll 1
  for (int seg = 0; seg < 2; ++seg) {
    const int qt = seg == 0 ? pairx : 31 - pairx;
    const int q0 = qt * 64;
    const int wq_abs = q0 + wq;

    bf16x8 qf[4];
    {
      const bf16* rp = Qh + (size_t)(wq_abs + l16) * rs + quad * 8;
#pragma unroll
      for (int t = 0; t < 4; ++t) qf[t] = *(const bf16x8*)(rp + t * 32);
    }

    f32x4 o_acc[8];
#pragma unroll
    for (int j = 0; j < 8; ++j) o_acc[j] = (f32x4)0.0f;
    float m_col = NEG_SENTINEL;
    float l_col = 0.0f;

    const int nkt = qt + 1;
#pragma unroll 1
    for (int kt = 0; kt < nkt; ++kt) {
      const int kk0 = kt * ABK;
      __syncthreads();

#pragma unroll
      for (int g = 0; g < 4; ++g) {
        int p   = g * 256 + tid;
        int row = p >> 4, pos = p & 15;
        int cc  = pos ^ (row & 15);
        gload_lds16(Kh + (size_t)(kk0 + row) * rs + cc * 8, (char*)sK + (size_t)p * 16);
      }
#pragma unroll
      for (int g = 0; g < 4; ++g) {
        int p  = g * 256 + tid;
        int d  = p >> 3, pos = p & 7;
        int cc = pos ^ (d & 7);
        gload_lds16(Vth + (size_t)d * S_ + kk0 + cc * 8, (char*)sVT + (size_t)p * 16);
      }
      __syncthreads();

      if (kk0 <= wq_abs + 15) {
        f32x4 st[4];
#pragma unroll
        for (int jt = 0; jt < 4; ++jt) {
          bf16x8 kf[4];
#pragma unroll
          for (int t = 0; t < 4; ++t) {
            int pos = (t * 4 + quad) ^ l16;
            kf[t] = *(const bf16x8*)(sK + (jt * 16 + l16) * HD_ + pos * 8);
          }
          f32x4 a = (f32x4)0.0f;
#pragma unroll
          for (int t = 0; t < 4; ++t) a = mfma16(kf[t], qf[t], a);
          st[jt] = a;
        }

        if (kk0 + 63 > wq_abs) {
          int qcol = wq_abs + l16;
#pragma unroll
          for (int jt = 0; jt < 4; ++jt)
#pragma unroll
            for (int r = 0; r < 4; ++r) {
              int key = kk0 + jt * 16 + quad * 4 + r;
              if (key > qcol) st[jt][r] = NEG_SENTINEL;
            }
        }

        float mx = NEG_SENTINEL;
#pragma unroll
        for (int jt = 0; jt < 4; ++jt)
#pragma unroll
          for (int r = 0; r < 4; ++r) mx = fmaxf(mx, st[jt][r]);
        mx = fmaxf(mx, __shfl_xor(mx, 16, 64));
        mx = fmaxf(mx, __shfl_xor(mx, 32, 64));
        float m_new = fmaxf(m_col, mx);
        float alpha = exp2f(m_col - m_new);
        float ts = 0.0f;
#pragma unroll
        for (int jt = 0; jt < 4; ++jt) {
          bf16x4 pk;
#pragma unroll
          for (int r = 0; r < 4; ++r) {
            float p = exp2f(st[jt][r] - m_new);
            ts += p;
            pk[r] = (bf16)p;
          }
          *(bf16x4*)(sP + (wq + l16) * SPS + jt * 16 + quad * 4) = pk;
        }
        ts += __shfl_xor(ts, 16, 64);
        ts += __shfl_xor(ts, 32, 64);
        l_col = l_col * alpha + ts;
        m_col = m_new;
#pragma unroll
        for (int r = 0; r < 4; ++r) {
          float av = __shfl(alpha, quad * 4 + r, 64);
#pragma unroll
          for (int jd = 0; jd < 8; ++jd) o_acc[jd][r] *= av;
        }

#pragma unroll
        for (int ks = 0; ks < 2; ++ks) {
          bf16x8 pf = *(const bf16x8*)(sP + (wq + l16) * SPS + ks * 32 + quad * 8);
#pragma unroll
          for (int jd = 0; jd < 8; ++jd) {
            int pos = (ks * 4 + quad) ^ (l16 & 7);
            bf16x8 vf = *(const bf16x8*)(sVT + (jd * 16 + l16) * ABK + pos * 8);
            o_acc[jd] = mfma16(pf, vf, o_acc[jd]);
          }
        }
      }
    }

#pragma unroll
    for (int r = 0; r < 4; ++r) {
      float lv = __shfl(l_col, quad * 4 + r, 64);
      float inv_l = 1.0f / lv;
      int row = wq_abs + quad * 4 + r;
#pragma unroll
      for (int jd = 0; jd < 8; ++jd) {
        int colo = jd * 16 + l16;
        Oh[(size_t)row * D_ + colo] = (bf16)(o_acc[jd][r] * inv_l);
      }
    }
  }
}

// ---------------------------------------------------------------------------
extern "C" void kernel_launch(void* const* d_in, const int* in_sizes, int n_in,
                              void* d_out, int out_size, void* d_ws, size_t ws_size,
                              hipStream_t stream) {
  const float* x    = (const float*)d_in[0];
  const float* Wq   = (const float*)d_in[1];
  const float* Wk   = (const float*)d_in[2];
  const float* Wv   = (const float*)d_in[3];
  const float* Wo   = (const float*)d_in[4];
  const float* cosT = (const float*)d_in[5];
  const float* sinT = (const float*)d_in[6];
  float* out = (float*)d_out;

  const size_t NE = (size_t)B_ * S_ * D_;   // 8,388,608
  const size_t WE = (size_t)D_ * D_;        // 4,194,304
  const int M = B_ * S_;
  const int cvtX = (int)(NE / 1024);
  const int cvtW = (int)(WE / 1024);

  static bool attr_done = false;
  if (!attr_done) {
    (void)hipFuncSetAttribute(reinterpret_cast<const void*>(gemm_pipe<bf16>),
                              hipFuncAttributeMaxDynamicSharedMemorySize, PLDSB);
    (void)hipFuncSetAttribute(reinterpret_cast<const void*>(gemm_pipe<float>),
                              hipFuncAttributeMaxDynamicSharedMemorySize, PLDSB);
    attr_done = true;
  }

  if (ws_size >= (size_t)92274688) {
    // ---- fused-QKV path (88 MB): QKV(48) | xb(16) | Wqkv->ctx+Wo_b(24) ----
    bf16* QKV   = (bf16*)d_ws;              // (4096, 6144) row-major
    bf16* xb    = QKV + (size_t)M * 6144;
    bf16* Wqkv  = xb + NE;
    bf16* ctx   = Wqkv;                     // reuse after QKV GEMM
    bf16* Wob   = Wqkv + 2 * WE;
    bf16* Vt    = xb;                       // reuse after QKV GEMM

    cvt_f32_bf16<<<cvtX, 256, 0, stream>>>(x, xb);
    cvt_f32_bf16<<<cvtW, 256, 0, stream>>>(Wq, Wqkv);
    cvt_f32_bf16<<<cvtW, 256, 0, stream>>>(Wk, Wqkv + WE);
    cvt_f32_bf16<<<cvtW, 256, 0, stream>>>(Wv, Wqkv + 2 * WE);
    // QKV GEMM: M=4096, N=6144 -> grid 48*16 = 768 = 3 blocks/CU balanced
    gemm_pipe<bf16><<<768, 512, PLDSB, stream>>>(xb, Wqkv, QKV, M, 3 * D_, D_, 3 * D_, 16);
    rope_qk<<<(B_ * S_ * H_ * 64) / 256, 256, 0, stream>>>(QKV, QKV + D_, cosT, sinT, 3 * D_);
    transpose_v<<<dim3(32, 2, 32), 256, 0, stream>>>(QKV + 2 * D_, Vt, 3 * D_);
    attn_fwd<<<512, 256, 0, stream>>>(QKV, QKV + D_, Vt, ctx, 3 * D_);
    cvt_f32_bf16<<<cvtW, 256, 0, stream>>>(Wo, Wob);
    // out GEMM: M=4096, N=2048 -> grid 16*16 = 256 = 1 block/CU balanced
    gemm_pipe<float><<<256, 512, PLDSB, stream>>>(ctx, Wob, out, M, D_, D_, D_, 16);
  } else {
    // ---- fallback (72 MB): separate GEMMs, legacy kernel ----
    bf16* Qb    = (bf16*)d_ws;
    bf16* Kb    = Qb + NE;
    bf16* Vb    = Kb + NE;
    bf16* Cb    = Vb + NE;                  // bf16(x) -> later Vt
    bf16* Wslot = Cb + NE;

    cvt_f32_bf16<<<cvtX, 256, 0, stream>>>(x, Cb);
    cvt_f32_bf16<<<cvtW, 256, 0, stream>>>(Wq, Wslot);
    gemm_xwt<bf16><<<dim3(16, 32), 256, 0, stream>>>(Cb, Wslot, Qb, M, D_, D_, D_);
    cvt_f32_bf16<<<cvtW, 256, 0, stream>>>(Wk, Wslot);
    gemm_xwt<bf16><<<dim3(16, 32), 256, 0, stream>>>(Cb, Wslot, Kb, M, D_, D_, D_);
    cvt_f32_bf16<<<cvtW, 256, 0, stream>>>(Wv, Wslot);
    gemm_xwt<bf16><<<dim3(16, 32), 256, 0, stream>>>(Cb, Wslot, Vb, M, D_, D_, D_);
    rope_qk<<<(B_ * S_ * H_ * 64) / 256, 256, 0, stream>>>(Qb, Kb, cosT, sinT, D_);
    transpose_v<<<dim3(32, 2, 32), 256, 0, stream>>>(Vb, Cb, D_);
    attn_fwd<<<512, 256, 0, stream>>>(Qb, Kb, Cb, Vb, D_);
    cvt_f32_bf16<<<cvtW, 256, 0, stream>>>(Wo, Wslot);
    gemm_xwt<float><<<dim3(16, 32), 256, 0, stream>>>(Vb, Wslot, out, M, D_, D_, D_);
  }
}

// Round 3
// 406.639 us; speedup vs baseline: 1.0089x; 1.0089x over previous
//
#include <hip/hip_runtime.h>
#include <cstdint>
#include <cmath>

#define B_ 2
#define S_ 2048
#define D_ 2048
#define H_ 16
#define HD_ 128

#define NEG_SENTINEL -1.0e30f

typedef __bf16 bf16;
typedef __attribute__((ext_vector_type(4))) __bf16 bf16x4;
typedef __attribute__((ext_vector_type(8))) __bf16 bf16x8;
typedef __attribute__((ext_vector_type(4))) float f32x4;

__device__ __forceinline__ void gload_lds16(const void* g, void* l) {
  __builtin_amdgcn_global_load_lds(
      (const __attribute__((address_space(1))) unsigned int*)g,
      (__attribute__((address_space(3))) unsigned int*)l, 16, 0, 0);
}

__device__ __forceinline__ f32x4 mfma16(bf16x8 a, bf16x8 b, f32x4 c) {
  return __builtin_amdgcn_mfma_f32_16x16x32_bf16(a, b, c, 0, 0, 0);
}

__device__ __forceinline__ void wg_barrier() {
  asm volatile("" ::: "memory");
  __builtin_amdgcn_s_barrier();
  asm volatile("" ::: "memory");
}

// ---------------------------------------------------------------------------
// fp32 -> bf16 convert. One thread = 4 elements.
// ---------------------------------------------------------------------------
__global__ __launch_bounds__(256) void cvt_f32_bf16(
    const float* __restrict__ in, bf16* __restrict__ out)
{
  int i = blockIdx.x * 256 + threadIdx.x;
  f32x4 v = ((const f32x4*)in)[i];
  bf16x4 o;
#pragma unroll
  for (int j = 0; j < 4; ++j) o[j] = (bf16)v[j];
  ((bf16x4*)out)[i] = o;
}

// ---------------------------------------------------------------------------
// Legacy GEMM (kept for fallback path): 128x128 tile, BK=64. (verified R3)
// ---------------------------------------------------------------------------
#define GTM 128
#define GTN 128
#define GBK 64

template <typename OT>
__global__ __launch_bounds__(256) void gemm_xwt(
    const bf16* __restrict__ A, const bf16* __restrict__ W, OT* __restrict__ C,
    int M, int N, int K, int ldc)
{
  __shared__ bf16 sA[GTM * GBK];
  __shared__ bf16 sB[GTN * GBK];
  const int tid  = threadIdx.x;
  const int wave = tid >> 6, lane = tid & 63;
  const int quad = lane >> 4, l16 = lane & 15;
  const int tm = blockIdx.y * GTM;
  const int tn = blockIdx.x * GTN;
  const int wm = (wave >> 1) * 64, wn = (wave & 1) * 64;

  f32x4 acc[4][4];
#pragma unroll
  for (int i = 0; i < 4; ++i)
#pragma unroll
    for (int j = 0; j < 4; ++j) acc[i][j] = (f32x4)0.0f;

  for (int k0 = 0; k0 < K; k0 += GBK) {
    __syncthreads();
#pragma unroll
    for (int g = 0; g < 4; ++g) {
      int gb  = (g * 4 + wave) * 64;
      int p   = gb + lane;
      int row = p >> 3, pos = p & 7;
      int cc  = pos ^ (row & 7);
      gload_lds16(A + (size_t)(tm + row) * K + k0 + cc * 8, (char*)sA + (size_t)gb * 16);
      gload_lds16(W + (size_t)(tn + row) * K + k0 + cc * 8, (char*)sB + (size_t)gb * 16);
    }
    __syncthreads();

#pragma unroll
    for (int t = 0; t < 2; ++t) {
      bf16x8 af[4], bfr[4];
#pragma unroll
      for (int i = 0; i < 4; ++i) {
        int rowa = wm + i * 16 + l16;
        int posa = (t * 4 + quad) ^ (rowa & 7);
        af[i] = *(const bf16x8*)(sA + rowa * GBK + posa * 8);
        int rowb = wn + i * 16 + l16;
        int posb = (t * 4 + quad) ^ (rowb & 7);
        bfr[i] = *(const bf16x8*)(sB + rowb * GBK + posb * 8);
      }
#pragma unroll
      for (int i = 0; i < 4; ++i)
#pragma unroll
        for (int j = 0; j < 4; ++j)
          acc[i][j] = mfma16(af[i], bfr[j], acc[i][j]);
    }
  }

#pragma unroll
  for (int i = 0; i < 4; ++i)
#pragma unroll
    for (int r = 0; r < 4; ++r) {
      int row = tm + wm + i * 16 + quad * 4 + r;
#pragma unroll
      for (int j = 0; j < 4; ++j) {
        int col = tn + wn + j * 16 + l16;
        C[(size_t)row * ldc + col] = (OT)acc[i][j][r];
      }
    }
}

// ---------------------------------------------------------------------------
// Phase-pipelined GEMM v3: 3-slot LDS ring, 2 K-tiles in flight.
// BM=256 x BN=128, BK=64, 512 thr (8 waves 2Mx4N, per-wave 128x32).
// LDS 144KB = 3 slots x (A 32KB + B 16KB). 2 phases per K-tile (split by
// M-quadrant; phase read-set == stage unit exactly, wave-uniform readiness):
//  p1(t): ds_read A-u0(slot)+B(slot), stage A-u0/u1(t+2)->slot[(t+2)%3],
//         bar, 16 MFMA, bar.
//  p2(t): ds_read A-u1(slot), stage B(t+2)->slot[(t+2)%3],
//         bar, 16 MFMA, vmcnt(6) [tail vmcnt(0)], bar.
// Ledger @ p2(t) vmcnt: in-flight (old->new) = A(t+1)[4] B(t+1)[2]
// A(t+2)[4] B(t+2)[2] = 12; vmcnt(6) retires tile t+1, issued 2-3 phases
// (~600-900cy) earlier -> covers L2-miss latency (R2 failure: depth was 1
// phase ~200cy -> stall; MfmaUtil 34%). Tail: t+2>=NT stages nothing ->
// vmcnt(0) retires tile t+1 exactly.
// Write-safety: slot[(t+2)%3] last read by tile t-1; those ds_reads retire
// before p2(t-1)'s final barrier; stage is issued after it.
// Accumulation per element identical to gemm_xwt (k ascending, fp32 acc).
// ---------------------------------------------------------------------------
#define PTM 256
#define PTN 128
#define PBK 64
#define PBUFB 49152   // bytes per slot: A 32768 + B 16384
#define PLDSB 147456  // 3 slots

// Stage A-unit u of K-tile kt_ into slot bi_: rows u*64+{0..63}, 128+u*64+{0..63}.
#define STAGE_AU(kt_, u_, bi_) do { \
    char* dstA_ = smem + ((bi_) * PBUFB); \
    _Pragma("unroll") \
    for (int g2_ = 0; g2_ < 2; ++g2_) { \
      int row0_ = (u_) * 64 + g2_ * 128 + wave * 8; \
      int row_  = row0_ + (lane >> 3); \
      int cc_   = (lane & 7) ^ (row_ & 7); \
      gload_lds16(A + (size_t)(tm + row_) * K + (size_t)(kt_) * PBK + cc_ * 8, \
                  dstA_ + row0_ * 128); \
    } } while (0)

#define STAGE_BF(kt_, bi_) do { \
    char* dstB_ = smem + ((bi_) * PBUFB) + 32768; \
    _Pragma("unroll") \
    for (int g2_ = 0; g2_ < 2; ++g2_) { \
      int row0_ = g2_ * 64 + wave * 8; \
      int row_  = row0_ + (lane >> 3); \
      int cc_   = (lane & 7) ^ (row_ & 7); \
      gload_lds16(W + (size_t)(tn + row_) * K + (size_t)(kt_) * PBK + cc_ * 8, \
                  dstB_ + row0_ * 128); \
    } } while (0)

template <typename OT>
__global__ __launch_bounds__(512, 2) void gemm_pipe(
    const bf16* __restrict__ A, const bf16* __restrict__ W, OT* __restrict__ C,
    int M, int N, int K, int ldc, int nby)
{
  extern __shared__ char smem[];
  const int tid  = threadIdx.x;
  const int wave = tid >> 6, lane = tid & 63;
  const int quad = lane >> 4, l16 = lane & 15;

  // XCD-chunked bijective swizzle (launcher guarantees gridDim.x % 8 == 0)
  const int nwg = (int)gridDim.x;
  const int cpx = nwg >> 3;
  const int wg  = ((int)blockIdx.x & 7) * cpx + ((int)blockIdx.x >> 3);
  const int bx = wg / nby, by = wg % nby;
  const int tm = by * PTM, tn = bx * PTN;
  const int wm = (wave >> 2) * 128, wn = (wave & 3) * 32;

  const int NT = K / PBK;

  f32x4 acc[8][2];
#pragma unroll
  for (int i = 0; i < 8; ++i)
#pragma unroll
    for (int j = 0; j < 2; ++j) acc[i][j] = (f32x4)0.0f;

  // prologue: stage tile0 -> slot0, tile1 -> slot1 (12 loads); vmcnt(6)
  // retires exactly tile0.
  STAGE_AU(0, 0, 0);
  STAGE_AU(0, 1, 0);
  STAGE_BF(0, 0);
  if (NT > 1) {
    STAGE_AU(1, 0, 1);
    STAGE_AU(1, 1, 1);
    STAGE_BF(1, 1);
    asm volatile("s_waitcnt vmcnt(6)" ::: "memory");
  } else {
    asm volatile("s_waitcnt vmcnt(0)" ::: "memory");
  }
  wg_barrier();

  int bi = 0;   // slot holding tile t
#pragma unroll 1
  for (int t = 0; t < NT; ++t) {
    const bf16* sAb = (const bf16*)(smem + bi * PBUFB);
    const bf16* sBb = sAb + 16384;   // +32768 bytes
    int bi2 = bi + 2; if (bi2 >= 3) bi2 -= 3;   // slot for tile t+2
    bf16x8 a[4][2], b[2][2];

    // -------- phase 1: q_m = 0 (A rows wm..wm+63 = A-unit0) --------
#pragma unroll
    for (int i = 0; i < 4; ++i)
#pragma unroll
      for (int t2 = 0; t2 < 2; ++t2) {
        int r  = wm + i * 16 + l16;
        int ps = (t2 * 4 + quad) ^ (r & 7);
        a[i][t2] = *(const bf16x8*)(sAb + r * 64 + ps * 8);
      }
#pragma unroll
    for (int j = 0; j < 2; ++j)
#pragma unroll
      for (int t2 = 0; t2 < 2; ++t2) {
        int r  = wn + j * 16 + l16;
        int ps = (t2 * 4 + quad) ^ (r & 7);
        b[j][t2] = *(const bf16x8*)(sBb + r * 64 + ps * 8);
      }
    if (t + 2 < NT) { STAGE_AU(t + 2, 0, bi2); STAGE_AU(t + 2, 1, bi2); }
    wg_barrier();
    __builtin_amdgcn_s_setprio(1);
#pragma unroll
    for (int i = 0; i < 4; ++i)
#pragma unroll
      for (int j = 0; j < 2; ++j)
#pragma unroll
        for (int t2 = 0; t2 < 2; ++t2)
          acc[i][j] = mfma16(a[i][t2], b[j][t2], acc[i][j]);
    __builtin_amdgcn_s_setprio(0);
    wg_barrier();

    // -------- phase 2: q_m = 1 (A rows wm+64..wm+127 = A-unit1) --------
#pragma unroll
    for (int i = 0; i < 4; ++i)
#pragma unroll
      for (int t2 = 0; t2 < 2; ++t2) {
        int r  = wm + 64 + i * 16 + l16;
        int ps = (t2 * 4 + quad) ^ (r & 7);
        a[i][t2] = *(const bf16x8*)(sAb + r * 64 + ps * 8);
      }
    if (t + 2 < NT) STAGE_BF(t + 2, bi2);
    wg_barrier();
    __builtin_amdgcn_s_setprio(1);
#pragma unroll
    for (int i = 0; i < 4; ++i)
#pragma unroll
      for (int j = 0; j < 2; ++j)
#pragma unroll
        for (int t2 = 0; t2 < 2; ++t2)
          acc[4 + i][j] = mfma16(a[i][t2], b[j][t2], acc[4 + i][j]);
    __builtin_amdgcn_s_setprio(0);
    if (t + 2 >= NT) { asm volatile("s_waitcnt vmcnt(0)" ::: "memory"); }
    else             { asm volatile("s_waitcnt vmcnt(6)" ::: "memory"); }
    wg_barrier();

    bi = bi + 1; if (bi >= 3) bi = 0;
  }

#pragma unroll
  for (int i = 0; i < 8; ++i)
#pragma unroll
    for (int r = 0; r < 4; ++r) {
      int row = tm + wm + i * 16 + quad * 4 + r;
#pragma unroll
      for (int j = 0; j < 2; ++j) {
        int col = tn + wn + j * 16 + l16;
        C[(size_t)row * ldc + col] = (OT)acc[i][j][r];
      }
    }
}

// ---------------------------------------------------------------------------
// RoPE in-place; Q pre-scaled by 1/sqrt(HD)*log2(e). Row stride rs.
// ---------------------------------------------------------------------------
__global__ __launch_bounds__(256) void rope_qk(
    bf16* __restrict__ Q, bf16* __restrict__ Kk,
    const float* __restrict__ cosT, const float* __restrict__ sinT, int rs)
{
  const float kappa = 0.08838834764831845f * 1.4426950408889634f;
  int t = blockIdx.x * 256 + threadIdx.x;
  int d = t & 63;
  int h = (t >> 6) & (H_ - 1);
  int s = (t >> 10) & (S_ - 1);
  int b = t >> 21;
  size_t base = ((size_t)(b * S_ + s)) * rs + (size_t)h * HD_;
  float c1 = cosT[s * HD_ + d];
  float s1 = sinT[s * HD_ + d];
  float c2 = cosT[s * HD_ + d + 64];
  float s2 = sinT[s * HD_ + d + 64];
  {
    float x1 = (float)Q[base + d], x2 = (float)Q[base + d + 64];
    Q[base + d]      = (bf16)((x1 * c1 - x2 * s1) * kappa);
    Q[base + d + 64] = (bf16)((x2 * c2 + x1 * s2) * kappa);
  }
  {
    float x1 = (float)Kk[base + d], x2 = (float)Kk[base + d + 64];
    Kk[base + d]      = (bf16)(x1 * c1 - x2 * s1);
    Kk[base + d + 64] = (bf16)(x2 * c2 + x1 * s2);
  }
}

// ---------------------------------------------------------------------------
// V transpose: V[b][s][...] (row stride rs) -> Vt[(b*H+h)*128+d][s].
// ---------------------------------------------------------------------------
__global__ __launch_bounds__(256) void transpose_v(
    const bf16* __restrict__ V, bf16* __restrict__ Vt, int rs)
{
  __shared__ bf16 sT[64 * 72];
  const int tid = threadIdx.x;
  const int si = blockIdx.x;
  const int di = blockIdx.y;
  const int bh = blockIdx.z;
  const int b  = bh >> 4, h = bh & 15;

  const bf16* src = V + (size_t)b * S_ * rs + (size_t)h * HD_ + di * 64;
  bf16*       dst = Vt + ((size_t)bh * HD_ + di * 64) * S_ + si * 64;

#pragma unroll
  for (int half = 0; half < 2; ++half) {
    int r  = half * 32 + (tid >> 3);
    int c0 = (tid & 7) * 8;
    bf16x8 v = *(const bf16x8*)(src + (size_t)(si * 64 + r) * rs + c0);
    *(bf16x8*)(sT + r * 72 + c0) = v;
  }
  __syncthreads();
#pragma unroll
  for (int half = 0; half < 2; ++half) {
    int dr = half * 32 + (tid >> 3);
    int c0 = (tid & 7) * 8;
    bf16x8 o;
#pragma unroll
    for (int j = 0; j < 8; ++j) o[j] = sT[(c0 + j) * 72 + dr];
    *(bf16x8*)(dst + (size_t)dr * S_ + c0) = o;
  }
}

// ---------------------------------------------------------------------------
// Flash attention fwd, causal. (measured-best R8 balanced-pair structure)
// ---------------------------------------------------------------------------
#define ABK 64
#define SPS 72

__global__ __launch_bounds__(256) void attn_fwd(
    const bf16* __restrict__ Q, const bf16* __restrict__ K,
    const bf16* __restrict__ Vt, bf16* __restrict__ O, int rs)
{
  __shared__ bf16 sK[ABK * HD_];     // 16 KB
  __shared__ bf16 sVT[HD_ * ABK];    // 16 KB
  __shared__ bf16 sP[64 * SPS];      // 9 KB   (total 41 KB)

  const int tid  = threadIdx.x;
  const int wave = tid >> 6, lane = tid & 63;
  const int quad = lane >> 4, l16 = lane & 15;

  const int lin   = (int)blockIdx.x;
  const int low3  = lin & 7;
  const int rest  = lin >> 3;
  const int pairx = rest & 15;
  const int colhi = rest >> 4;
  const int col   = low3 + (colhi << 3);
  const int b = col >> 4, h = col & 15;

  const bf16* Qh  = Q + (size_t)b * S_ * rs + (size_t)h * HD_;
  const bf16* Kh  = K + (size_t)b * S_ * rs + (size_t)h * HD_;
  const bf16* Vth = Vt + ((size_t)(b * H_ + h) * HD_) * S_;
  bf16*       Oh  = O + (size_t)b * S_ * D_ + (size_t)h * HD_;

  const int wq = wave * 16;

#pragma unroll 1
  for (int seg = 0; seg < 2; ++seg) {
    const int qt = seg == 0 ? pairx : 31 - pairx;
    const int q0 = qt * 64;
    const int wq_abs = q0 + wq;

    bf16x8 qf[4];
    {
      const bf16* rp = Qh + (size_t)(wq_abs + l16) * rs + quad * 8;
#pragma unroll
      for (int t = 0; t < 4; ++t) qf[t] = *(const bf16x8*)(rp + t * 32);
    }

    f32x4 o_acc[8];
#pragma unroll
    for (int j = 0; j < 8; ++j) o_acc[j] = (f32x4)0.0f;
    float m_col = NEG_SENTINEL;
    float l_col = 0.0f;

    const int nkt = qt + 1;
#pragma unroll 1
    for (int kt = 0; kt < nkt; ++kt) {
      const int kk0 = kt * ABK;
      __syncthreads();

#pragma unroll
      for (int g = 0; g < 4; ++g) {
        int p   = g * 256 + tid;
        int row = p >> 4, pos = p & 15;
        int cc  = pos ^ (row & 15);
        gload_lds16(Kh + (size_t)(kk0 + row) * rs + cc * 8, (char*)sK + (size_t)p * 16);
      }
#pragma unroll
      for (int g = 0; g < 4; ++g) {
        int p  = g * 256 + tid;
        int d  = p >> 3, pos = p & 7;
        int cc = pos ^ (d & 7);
        gload_lds16(Vth + (size_t)d * S_ + kk0 + cc * 8, (char*)sVT + (size_t)p * 16);
      }
      __syncthreads();

      if (kk0 <= wq_abs + 15) {
        f32x4 st[4];
#pragma unroll
        for (int jt = 0; jt < 4; ++jt) {
          bf16x8 kf[4];
#pragma unroll
          for (int t = 0; t < 4; ++t) {
            int pos = (t * 4 + quad) ^ l16;
            kf[t] = *(const bf16x8*)(sK + (jt * 16 + l16) * HD_ + pos * 8);
          }
          f32x4 a = (f32x4)0.0f;
#pragma unroll
          for (int t = 0; t < 4; ++t) a = mfma16(kf[t], qf[t], a);
          st[jt] = a;
        }

        if (kk0 + 63 > wq_abs) {
          int qcol = wq_abs + l16;
#pragma unroll
          for (int jt = 0; jt < 4; ++jt)
#pragma unroll
            for (int r = 0; r < 4; ++r) {
              int key = kk0 + jt * 16 + quad * 4 + r;
              if (key > qcol) st[jt][r] = NEG_SENTINEL;
            }
        }

        float mx = NEG_SENTINEL;
#pragma unroll
        for (int jt = 0; jt < 4; ++jt)
#pragma unroll
          for (int r = 0; r < 4; ++r) mx = fmaxf(mx, st[jt][r]);
        mx = fmaxf(mx, __shfl_xor(mx, 16, 64));
        mx = fmaxf(mx, __shfl_xor(mx, 32, 64));
        float m_new = fmaxf(m_col, mx);
        float alpha = exp2f(m_col - m_new);
        float ts = 0.0f;
#pragma unroll
        for (int jt = 0; jt < 4; ++jt) {
          bf16x4 pk;
#pragma unroll
          for (int r = 0; r < 4; ++r) {
            float p = exp2f(st[jt][r] - m_new);
            ts += p;
            pk[r] = (bf16)p;
          }
          *(bf16x4*)(sP + (wq + l16) * SPS + jt * 16 + quad * 4) = pk;
        }
        ts += __shfl_xor(ts, 16, 64);
        ts += __shfl_xor(ts, 32, 64);
        l_col = l_col * alpha + ts;
        m_col = m_new;
#pragma unroll
        for (int r = 0; r < 4; ++r) {
          float av = __shfl(alpha, quad * 4 + r, 64);
#pragma unroll
          for (int jd = 0; jd < 8; ++jd) o_acc[jd][r] *= av;
        }

#pragma unroll
        for (int ks = 0; ks < 2; ++ks) {
          bf16x8 pf = *(const bf16x8*)(sP + (wq + l16) * SPS + ks * 32 + quad * 8);
#pragma unroll
          for (int jd = 0; jd < 8; ++jd) {
            int pos = (ks * 4 + quad) ^ (l16 & 7);
            bf16x8 vf = *(const bf16x8*)(sVT + (jd * 16 + l16) * ABK + pos * 8);
            o_acc[jd] = mfma16(pf, vf, o_acc[jd]);
          }
        }
      }
    }

#pragma unroll
    for (int r = 0; r < 4; ++r) {
      float lv = __shfl(l_col, quad * 4 + r, 64);
      float inv_l = 1.0f / lv;
      int row = wq_abs + quad * 4 + r;
#pragma unroll
      for (int jd = 0; jd < 8; ++jd) {
        int colo = jd * 16 + l16;
        Oh[(size_t)row * D_ + colo] = (bf16)(o_acc[jd][r] * inv_l);
      }
    }
  }
}

// ---------------------------------------------------------------------------
extern "C" void kernel_launch(void* const* d_in, const int* in_sizes, int n_in,
                              void* d_out, int out_size, void* d_ws, size_t ws_size,
                              hipStream_t stream) {
  const float* x    = (const float*)d_in[0];
  const float* Wq   = (const float*)d_in[1];
  const float* Wk   = (const float*)d_in[2];
  const float* Wv   = (const float*)d_in[3];
  const float* Wo   = (const float*)d_in[4];
  const float* cosT = (const float*)d_in[5];
  const float* sinT = (const float*)d_in[6];
  float* out = (float*)d_out;

  const size_t NE = (size_t)B_ * S_ * D_;   // 8,388,608
  const size_t WE = (size_t)D_ * D_;        // 4,194,304
  const int M = B_ * S_;
  const int cvtX = (int)(NE / 1024);
  const int cvtW = (int)(WE / 1024);

  static bool attr_done = false;
  if (!attr_done) {
    (void)hipFuncSetAttribute(reinterpret_cast<const void*>(gemm_pipe<bf16>),
                              hipFuncAttributeMaxDynamicSharedMemorySize, PLDSB);
    (void)hipFuncSetAttribute(reinterpret_cast<const void*>(gemm_pipe<float>),
                              hipFuncAttributeMaxDynamicSharedMemorySize, PLDSB);
    attr_done = true;
  }

  if (ws_size >= (size_t)92274688) {
    // ---- fused-QKV path (88 MB): QKV(48) | xb(16) | Wqkv->ctx+Wo_b(24) ----
    bf16* QKV   = (bf16*)d_ws;              // (4096, 6144) row-major
    bf16* xb    = QKV + (size_t)M * 6144;
    bf16* Wqkv  = xb + NE;
    bf16* ctx   = Wqkv;                     // reuse after QKV GEMM
    bf16* Wob   = Wqkv + 2 * WE;
    bf16* Vt    = xb;                       // reuse after QKV GEMM

    cvt_f32_bf16<<<cvtX, 256, 0, stream>>>(x, xb);
    cvt_f32_bf16<<<cvtW, 256, 0, stream>>>(Wq, Wqkv);
    cvt_f32_bf16<<<cvtW, 256, 0, stream>>>(Wk, Wqkv + WE);
    cvt_f32_bf16<<<cvtW, 256, 0, stream>>>(Wv, Wqkv + 2 * WE);
    // QKV GEMM: M=4096, N=6144 -> grid 48*16 = 768 = 3 blocks/CU balanced
    gemm_pipe<bf16><<<768, 512, PLDSB, stream>>>(xb, Wqkv, QKV, M, 3 * D_, D_, 3 * D_, 16);
    rope_qk<<<(B_ * S_ * H_ * 64) / 256, 256, 0, stream>>>(QKV, QKV + D_, cosT, sinT, 3 * D_);
    transpose_v<<<dim3(32, 2, 32), 256, 0, stream>>>(QKV + 2 * D_, Vt, 3 * D_);
    attn_fwd<<<512, 256, 0, stream>>>(QKV, QKV + D_, Vt, ctx, 3 * D_);
    cvt_f32_bf16<<<cvtW, 256, 0, stream>>>(Wo, Wob);
    // out GEMM: M=4096, N=2048 -> grid 16*16 = 256 = 1 block/CU balanced
    gemm_pipe<float><<<256, 512, PLDSB, stream>>>(ctx, Wob, out, M, D_, D_, D_, 16);
  } else {
    // ---- fallback (72 MB): separate GEMMs, legacy kernel ----
    bf16* Qb    = (bf16*)d_ws;
    bf16* Kb    = Qb + NE;
    bf16* Vb    = Kb + NE;
    bf16* Cb    = Vb + NE;                  // bf16(x) -> later Vt
    bf16* Wslot = Cb + NE;

    cvt_f32_bf16<<<cvtX, 256, 0, stream>>>(x, Cb);
    cvt_f32_bf16<<<cvtW, 256, 0, stream>>>(Wq, Wslot);
    gemm_xwt<bf16><<<dim3(16, 32), 256, 0, stream>>>(Cb, Wslot, Qb, M, D_, D_, D_);
    cvt_f32_bf16<<<cvtW, 256, 0, stream>>>(Wk, Wslot);
    gemm_xwt<bf16><<<dim3(16, 32), 256, 0, stream>>>(Cb, Wslot, Kb, M, D_, D_, D_);
    cvt_f32_bf16<<<cvtW, 256, 0, stream>>>(Wv, Wslot);
    gemm_xwt<bf16><<<dim3(16, 32), 256, 0, stream>>>(Cb, Wslot, Vb, M, D_, D_, D_);
    rope_qk<<<(B_ * S_ * H_ * 64) / 256, 256, 0, stream>>>(Qb, Kb, cosT, sinT, D_);
    transpose_v<<<dim3(32, 2, 32), 256, 0, stream>>>(Vb, Cb, D_);
    attn_fwd<<<512, 256, 0, stream>>>(Qb, Kb, Cb, Vb, D_);
    cvt_f32_bf16<<<cvtW, 256, 0, stream>>>(Wo, Wslot);
    gemm_xwt<float><<<dim3(16, 32), 256, 0, stream>>>(Vb, Wslot, out, M, D_, D_, D_);
  }
}

// Round 4
// 399.558 us; speedup vs baseline: 1.0268x; 1.0177x over previous
//
#include <hip/hip_runtime.h>
#include <cstdint>
#include <cmath>

#define B_ 2
#define S_ 2048
#define D_ 2048
#define H_ 16
#define HD_ 128

#define NEG_SENTINEL -1.0e30f

typedef __bf16 bf16;
typedef __attribute__((ext_vector_type(4))) __bf16 bf16x4;
typedef __attribute__((ext_vector_type(8))) __bf16 bf16x8;
typedef __attribute__((ext_vector_type(4))) float f32x4;

__device__ __forceinline__ void gload_lds16(const void* g, void* l) {
  __builtin_amdgcn_global_load_lds(
      (const __attribute__((address_space(1))) unsigned int*)g,
      (__attribute__((address_space(3))) unsigned int*)l, 16, 0, 0);
}

__device__ __forceinline__ f32x4 mfma16(bf16x8 a, bf16x8 b, f32x4 c) {
  return __builtin_amdgcn_mfma_f32_16x16x32_bf16(a, b, c, 0, 0, 0);
}

__device__ __forceinline__ void wg_barrier() {
  asm volatile("" ::: "memory");
  __builtin_amdgcn_s_barrier();
  asm volatile("" ::: "memory");
}

// ---------------------------------------------------------------------------
// fp32 -> bf16 convert. One thread = 4 elements.
// ---------------------------------------------------------------------------
__global__ __launch_bounds__(256) void cvt_f32_bf16(
    const float* __restrict__ in, bf16* __restrict__ out)
{
  int i = blockIdx.x * 256 + threadIdx.x;
  f32x4 v = ((const f32x4*)in)[i];
  bf16x4 o;
#pragma unroll
  for (int j = 0; j < 4; ++j) o[j] = (bf16)v[j];
  ((bf16x4*)out)[i] = o;
}

// ---------------------------------------------------------------------------
// Legacy GEMM (verified): 128x128 tile, BK=64, 2 blocks/CU, ~897 TF.
// Used for out-projection (its grid 16x32=512 = 2 balanced rounds) and
// the fallback path.
// ---------------------------------------------------------------------------
#define GTM 128
#define GTN 128
#define GBK 64

template <typename OT>
__global__ __launch_bounds__(256) void gemm_xwt(
    const bf16* __restrict__ A, const bf16* __restrict__ W, OT* __restrict__ C,
    int M, int N, int K, int ldc)
{
  __shared__ bf16 sA[GTM * GBK];
  __shared__ bf16 sB[GTN * GBK];
  const int tid  = threadIdx.x;
  const int wave = tid >> 6, lane = tid & 63;
  const int quad = lane >> 4, l16 = lane & 15;
  const int tm = blockIdx.y * GTM;
  const int tn = blockIdx.x * GTN;
  const int wm = (wave >> 1) * 64, wn = (wave & 1) * 64;

  f32x4 acc[4][4];
#pragma unroll
  for (int i = 0; i < 4; ++i)
#pragma unroll
    for (int j = 0; j < 4; ++j) acc[i][j] = (f32x4)0.0f;

  for (int k0 = 0; k0 < K; k0 += GBK) {
    __syncthreads();
#pragma unroll
    for (int g = 0; g < 4; ++g) {
      int gb  = (g * 4 + wave) * 64;
      int p   = gb + lane;
      int row = p >> 3, pos = p & 7;
      int cc  = pos ^ (row & 7);
      gload_lds16(A + (size_t)(tm + row) * K + k0 + cc * 8, (char*)sA + (size_t)gb * 16);
      gload_lds16(W + (size_t)(tn + row) * K + k0 + cc * 8, (char*)sB + (size_t)gb * 16);
    }
    __syncthreads();

#pragma unroll
    for (int t = 0; t < 2; ++t) {
      bf16x8 af[4], bfr[4];
#pragma unroll
      for (int i = 0; i < 4; ++i) {
        int rowa = wm + i * 16 + l16;
        int posa = (t * 4 + quad) ^ (rowa & 7);
        af[i] = *(const bf16x8*)(sA + rowa * GBK + posa * 8);
        int rowb = wn + i * 16 + l16;
        int posb = (t * 4 + quad) ^ (rowb & 7);
        bfr[i] = *(const bf16x8*)(sB + rowb * GBK + posb * 8);
      }
#pragma unroll
      for (int i = 0; i < 4; ++i)
#pragma unroll
        for (int j = 0; j < 4; ++j)
          acc[i][j] = mfma16(af[i], bfr[j], acc[i][j]);
    }
  }

#pragma unroll
  for (int i = 0; i < 4; ++i)
#pragma unroll
    for (int r = 0; r < 4; ++r) {
      int row = tm + wm + i * 16 + quad * 4 + r;
#pragma unroll
      for (int j = 0; j < 4; ++j) {
        int col = tn + wn + j * 16 + l16;
        C[(size_t)row * ldc + col] = (OT)acc[i][j][r];
      }
    }
}

// ---------------------------------------------------------------------------
// 8-phase 256^2 GEMM (m201-template port): C[m][n] = sum_k A[m][k]*W[n][k].
// BM=BN=256, BK=64, 512 thr, 8 waves 2Mx4N, per-wave C = 128x64 (32 f32x4).
// LDS 128KB: buf0 (even tile) | buf1 (odd tile); each = A-lo|A-hi|B-lo|B-hi
// 16KB halves (half = 128 rows x 64 k). One iteration = 2 K-tiles, 8 phases.
// Phase p: {ds_read frag subtile; stage 1 half (2 gload_lds); bar;
//           lgkmcnt(0); setprio(1); 16 MFMA (one C-quadrant x K=64);
//           setprio(0); [vmcnt @p4/p8]; bar}.
// Gray-code quadrants per tile: (rh0,ch0) 12 rd, (rh0,ch1) 4 rd,
// (rh1,ch1) 8 rd, (rh1,ch0) 0 rd  -> avg 6KB/wave/phase (R2/R3 failure:
// 640 B LDS per MFMA; here 375 B -> reads hide under MFMA).
// Stage schedule (earliest-free slots, ledger-verified):
//   p1: A-lo(t1)->buf1   p2: A-hi(t1)->buf1   [buf1.A free after prev p7]
//   p3: B-lo(t0+2)->buf0 p4: B-hi(t0+2)->buf0 [buf0.B free after p2]
//   p5: A-lo(t0+2)->buf0 p6: A-hi(t0+2)->buf0 [buf0.A free after p3]
//   p7: B-lo(t1+2)->buf1 p8: B-hi(t1+2)->buf1 [buf1.B free after p6]
// vmcnt(4) at p4 (retires B(t1)@p7',p8' + A(t1)@p1,p2; leaves p3,p4) and
// at p8 (retires B(t0+2)@p3,p4 + A(t0+2)@p5,p6; leaves p7,p8). Last
// iteration stages only p1,p2 -> vmcnt(0) at p4, none at p8.
// Requires K%128==0, K>=256. Accumulation identical to gemm_xwt
// (tiles ascending, k ascending, fp32) -> same numerics.
// ---------------------------------------------------------------------------
#define QTM 256
#define QTN 256
#define QBK 64
#define QHALF 16384
#define QBUF 65536
#define QLDS 131072

#define QSTAGE_A(kt_, h_, bi_) do { \
    char* dst_ = smem + (bi_) * QBUF + (h_) * QHALF; \
    _Pragma("unroll") \
    for (int g_ = 0; g_ < 2; ++g_) { \
      int p_   = g_ * 512 + tid; \
      int row_ = p_ >> 3; \
      int cc_  = (p_ & 7) ^ (row_ & 7); \
      gload_lds16(A + (size_t)(tm + (h_) * 128 + row_) * K + (size_t)(kt_) * QBK + cc_ * 8, \
                  dst_ + (size_t)p_ * 16); \
    } } while (0)

#define QSTAGE_B(kt_, h_, bi_) do { \
    char* dst_ = smem + (bi_) * QBUF + 32768 + (h_) * QHALF; \
    _Pragma("unroll") \
    for (int g_ = 0; g_ < 2; ++g_) { \
      int p_   = g_ * 512 + tid; \
      int row_ = p_ >> 3; \
      int cc_  = (p_ & 7) ^ (row_ & 7); \
      gload_lds16(W + (size_t)(tn + (h_) * 128 + row_) * K + (size_t)(kt_) * QBK + cc_ * 8, \
                  dst_ + (size_t)p_ * 16); \
    } } while (0)

#define QREAD_A(Ab_, rh_) \
    _Pragma("unroll") \
    for (int i_ = 0; i_ < 4; ++i_) \
    _Pragma("unroll") \
    for (int t2_ = 0; t2_ < 2; ++t2_) { \
      int rr_ = (rh_) * 64 + i_ * 16 + l16; \
      int ps_ = (t2_ * 4 + quad) ^ (rr_ & 7); \
      a[i_][t2_] = *(const bf16x8*)((Ab_) + rr_ * 64 + ps_ * 8); \
    }

#define QREAD_B(Bb_, bv_, ch_) \
    _Pragma("unroll") \
    for (int j_ = 0; j_ < 2; ++j_) \
    _Pragma("unroll") \
    for (int t2_ = 0; t2_ < 2; ++t2_) { \
      int rb_ = wn64 + (ch_) * 32 + j_ * 16 + l16; \
      int ps_ = (t2_ * 4 + quad) ^ (rb_ & 7); \
      bv_[j_][t2_] = *(const bf16x8*)((Bb_) + rb_ * 64 + ps_ * 8); \
    }

#define QMFMA(rh_, ch_, bv_) \
    __builtin_amdgcn_s_setprio(1); \
    _Pragma("unroll") \
    for (int i_ = 0; i_ < 4; ++i_) \
    _Pragma("unroll") \
    for (int j_ = 0; j_ < 2; ++j_) \
    _Pragma("unroll") \
    for (int t2_ = 0; t2_ < 2; ++t2_) \
      acc[(rh_) * 4 + i_][(ch_) * 2 + j_] = \
          mfma16(a[i_][t2_], bv_[j_][t2_], acc[(rh_) * 4 + i_][(ch_) * 2 + j_]); \
    __builtin_amdgcn_s_setprio(0);

#define LGK0()  asm volatile("s_waitcnt lgkmcnt(0)" ::: "memory")
#define LGK8()  asm volatile("s_waitcnt lgkmcnt(8)" ::: "memory")
#define VM4()   asm volatile("s_waitcnt vmcnt(4)" ::: "memory")
#define VM0()   asm volatile("s_waitcnt vmcnt(0)" ::: "memory")

__global__ __launch_bounds__(512, 2) void gemm_8ph(
    const bf16* __restrict__ A, const bf16* __restrict__ W, bf16* __restrict__ C,
    int M, int N, int K, int ldc, int nby)
{
  extern __shared__ char smem[];
  const int tid  = threadIdx.x;
  const int wave = tid >> 6, lane = tid & 63;
  const int quad = lane >> 4, l16 = lane & 15;

  // XCD-chunked swizzle (gridDim.x % 8 == 0 guaranteed by launcher)
  const int nwg = (int)gridDim.x;
  const int cpx = nwg >> 3;
  const int wg  = ((int)blockIdx.x & 7) * cpx + ((int)blockIdx.x >> 3);
  const int bx = wg / nby, by = wg % nby;
  const int tm = by * QTM, tn = bx * QTN;
  const int wm = (wave >> 2) * 128;          // 0 or 128
  const int wn = (wave & 3) * 64;            // 0,64,128,192
  const int wn64 = wn & 64;

  // per-wave LDS bases (region-selected by wave position; halves 128-aligned)
  const bf16* A0 = (const bf16*)(smem + (wm >> 7) * QHALF);
  const bf16* B0 = (const bf16*)(smem + 32768 + (wn >> 7) * QHALF);
  const bf16* A1 = (const bf16*)(smem + QBUF + (wm >> 7) * QHALF);
  const bf16* B1 = (const bf16*)(smem + QBUF + 32768 + (wn >> 7) * QHALF);

  const int NT = K / QBK;        // even, >= 4
  const int NI = NT >> 1;

  f32x4 acc[8][4];
#pragma unroll
  for (int i = 0; i < 8; ++i)
#pragma unroll
    for (int j = 0; j < 4; ++j) acc[i][j] = (f32x4)0.0f;

  bf16x8 a[4][2], b0[2][2], b1[2][2];

  // prologue: tile0 (A+B -> buf0, 8 loads) + B(1) -> buf1 (4 loads).
  // vmcnt(4) retires exactly tile0; A(1) staged at p1/p2 of iteration 0.
  QSTAGE_A(0, 0, 0);
  QSTAGE_A(0, 1, 0);
  QSTAGE_B(0, 0, 0);
  QSTAGE_B(0, 1, 0);
  QSTAGE_B(1, 0, 1);
  QSTAGE_B(1, 1, 1);
  VM4();
  wg_barrier();

#pragma unroll 1
  for (int it = 0; it < NI; ++it) {
    const int t0 = it * 2, t1 = t0 + 1;
    const bool last = (it == NI - 1);

    // ---------------- phase 1: tile t0, quadrant (rh0, ch0) ----------------
    QREAD_A(A0, 0);
    QREAD_B(B0, b0, 0);
    QSTAGE_A(t1, 0, 1);
    LGK8();
    wg_barrier();
    LGK0();
    QMFMA(0, 0, b0);
    wg_barrier();

    // ---------------- phase 2: (rh0, ch1) ----------------
    QREAD_B(B0, b1, 1);
    QSTAGE_A(t1, 1, 1);
    wg_barrier();
    LGK0();
    QMFMA(0, 1, b1);
    wg_barrier();

    // ---------------- phase 3: (rh1, ch1) ----------------
    QREAD_A(A0, 1);
    if (!last) QSTAGE_B(t0 + 2, 0, 0);
    wg_barrier();
    LGK0();
    QMFMA(1, 1, b1);
    wg_barrier();

    // ---------------- phase 4: (rh1, ch0), 0 reads ----------------
    if (!last) QSTAGE_B(t0 + 2, 1, 0);
    wg_barrier();
    QMFMA(1, 0, b0);
    if (last) { VM0(); } else { VM4(); }
    wg_barrier();

    // ---------------- phase 5: tile t1, quadrant (rh0, ch0) ----------------
    QREAD_A(A1, 0);
    QREAD_B(B1, b0, 0);
    if (!last) QSTAGE_A(t0 + 2, 0, 0);
    LGK8();
    wg_barrier();
    LGK0();
    QMFMA(0, 0, b0);
    wg_barrier();

    // ---------------- phase 6: (rh0, ch1) ----------------
    QREAD_B(B1, b1, 1);
    if (!last) QSTAGE_A(t0 + 2, 1, 0);
    wg_barrier();
    LGK0();
    QMFMA(0, 1, b1);
    wg_barrier();

    // ---------------- phase 7: (rh1, ch1) ----------------
    QREAD_A(A1, 1);
    if (!last) QSTAGE_B(t1 + 2, 0, 1);
    wg_barrier();
    LGK0();
    QMFMA(1, 1, b1);
    wg_barrier();

    // ---------------- phase 8: (rh1, ch0), 0 reads ----------------
    if (!last) QSTAGE_B(t1 + 2, 1, 1);
    wg_barrier();
    QMFMA(1, 0, b0);
    if (!last) { VM4(); }
    wg_barrier();
  }

  // epilogue: 32 frags; row = tm+wm+rh*64+i*16+quad*4+r, col = tn+wn+jj*16+l16
#pragma unroll
  for (int ii = 0; ii < 8; ++ii)
#pragma unroll
    for (int r = 0; r < 4; ++r) {
      int row = tm + wm + (ii >> 2) * 64 + (ii & 3) * 16 + quad * 4 + r;
#pragma unroll
      for (int jj = 0; jj < 4; ++jj) {
        int col = tn + wn + jj * 16 + l16;
        C[(size_t)row * ldc + col] = (bf16)acc[ii][jj][r];
      }
    }
}

// ---------------------------------------------------------------------------
// RoPE in-place; Q pre-scaled by 1/sqrt(HD)*log2(e). Row stride rs.
// ---------------------------------------------------------------------------
__global__ __launch_bounds__(256) void rope_qk(
    bf16* __restrict__ Q, bf16* __restrict__ Kk,
    const float* __restrict__ cosT, const float* __restrict__ sinT, int rs)
{
  const float kappa = 0.08838834764831845f * 1.4426950408889634f;
  int t = blockIdx.x * 256 + threadIdx.x;
  int d = t & 63;
  int h = (t >> 6) & (H_ - 1);
  int s = (t >> 10) & (S_ - 1);
  int b = t >> 21;
  size_t base = ((size_t)(b * S_ + s)) * rs + (size_t)h * HD_;
  float c1 = cosT[s * HD_ + d];
  float s1 = sinT[s * HD_ + d];
  float c2 = cosT[s * HD_ + d + 64];
  float s2 = sinT[s * HD_ + d + 64];
  {
    float x1 = (float)Q[base + d], x2 = (float)Q[base + d + 64];
    Q[base + d]      = (bf16)((x1 * c1 - x2 * s1) * kappa);
    Q[base + d + 64] = (bf16)((x2 * c2 + x1 * s2) * kappa);
  }
  {
    float x1 = (float)Kk[base + d], x2 = (float)Kk[base + d + 64];
    Kk[base + d]      = (bf16)(x1 * c1 - x2 * s1);
    Kk[base + d + 64] = (bf16)(x2 * c2 + x1 * s2);
  }
}

// ---------------------------------------------------------------------------
// V transpose: V[b][s][...] (row stride rs) -> Vt[(b*H+h)*128+d][s].
// ---------------------------------------------------------------------------
__global__ __launch_bounds__(256) void transpose_v(
    const bf16* __restrict__ V, bf16* __restrict__ Vt, int rs)
{
  __shared__ bf16 sT[64 * 72];
  const int tid = threadIdx.x;
  const int si = blockIdx.x;
  const int di = blockIdx.y;
  const int bh = blockIdx.z;
  const int b  = bh >> 4, h = bh & 15;

  const bf16* src = V + (size_t)b * S_ * rs + (size_t)h * HD_ + di * 64;
  bf16*       dst = Vt + ((size_t)bh * HD_ + di * 64) * S_ + si * 64;

#pragma unroll
  for (int half = 0; half < 2; ++half) {
    int r  = half * 32 + (tid >> 3);
    int c0 = (tid & 7) * 8;
    bf16x8 v = *(const bf16x8*)(src + (size_t)(si * 64 + r) * rs + c0);
    *(bf16x8*)(sT + r * 72 + c0) = v;
  }
  __syncthreads();
#pragma unroll
  for (int half = 0; half < 2; ++half) {
    int dr = half * 32 + (tid >> 3);
    int c0 = (tid & 7) * 8;
    bf16x8 o;
#pragma unroll
    for (int j = 0; j < 8; ++j) o[j] = sT[(c0 + j) * 72 + dr];
    *(bf16x8*)(dst + (size_t)dr * S_ + c0) = o;
  }
}

// ---------------------------------------------------------------------------
// Flash attention fwd, causal. (measured-best R8 balanced-pair structure)
// ---------------------------------------------------------------------------
#define ABK 64
#define SPS 72

__global__ __launch_bounds__(256) void attn_fwd(
    const bf16* __restrict__ Q, const bf16* __restrict__ K,
    const bf16* __restrict__ Vt, bf16* __restrict__ O, int rs)
{
  __shared__ bf16 sK[ABK * HD_];     // 16 KB
  __shared__ bf16 sVT[HD_ * ABK];    // 16 KB
  __shared__ bf16 sP[64 * SPS];      // 9 KB   (total 41 KB)

  const int tid  = threadIdx.x;
  const int wave = tid >> 6, lane = tid & 63;
  const int quad = lane >> 4, l16 = lane & 15;

  const int lin   = (int)blockIdx.x;
  const int low3  = lin & 7;
  const int rest  = lin >> 3;
  const int pairx = rest & 15;
  const int colhi = rest >> 4;
  const int col   = low3 + (colhi << 3);
  const int b = col >> 4, h = col & 15;

  const bf16* Qh  = Q + (size_t)b * S_ * rs + (size_t)h * HD_;
  const bf16* Kh  = K + (size_t)b * S_ * rs + (size_t)h * HD_;
  const bf16* Vth = Vt + ((size_t)(b * H_ + h) * HD_) * S_;
  bf16*       Oh  = O + (size_t)b * S_ * D_ + (size_t)h * HD_;

  const int wq = wave * 16;

#pragma unroll 1
  for (int seg = 0; seg < 2; ++seg) {
    const int qt = seg == 0 ? pairx : 31 - pairx;
    const int q0 = qt * 64;
    const int wq_abs = q0 + wq;

    bf16x8 qf[4];
    {
      const bf16* rp = Qh + (size_t)(wq_abs + l16) * rs + quad * 8;
#pragma unroll
      for (int t = 0; t < 4; ++t) qf[t] = *(const bf16x8*)(rp + t * 32);
    }

    f32x4 o_acc[8];
#pragma unroll
    for (int j = 0; j < 8; ++j) o_acc[j] = (f32x4)0.0f;
    float m_col = NEG_SENTINEL;
    float l_col = 0.0f;

    const int nkt = qt + 1;
#pragma unroll 1
    for (int kt = 0; kt < nkt; ++kt) {
      const int kk0 = kt * ABK;
      __syncthreads();

#pragma unroll
      for (int g = 0; g < 4; ++g) {
        int p   = g * 256 + tid;
        int row = p >> 4, pos = p & 15;
        int cc  = pos ^ (row & 15);
        gload_lds16(Kh + (size_t)(kk0 + row) * rs + cc * 8, (char*)sK + (size_t)p * 16);
      }
#pragma unroll
      for (int g = 0; g < 4; ++g) {
        int p  = g * 256 + tid;
        int d  = p >> 3, pos = p & 7;
        int cc = pos ^ (d & 7);
        gload_lds16(Vth + (size_t)d * S_ + kk0 + cc * 8, (char*)sVT + (size_t)p * 16);
      }
      __syncthreads();

      if (kk0 <= wq_abs + 15) {
        f32x4 st[4];
#pragma unroll
        for (int jt = 0; jt < 4; ++jt) {
          bf16x8 kf[4];
#pragma unroll
          for (int t = 0; t < 4; ++t) {
            int pos = (t * 4 + quad) ^ l16;
            kf[t] = *(const bf16x8*)(sK + (jt * 16 + l16) * HD_ + pos * 8);
          }
          f32x4 a2 = (f32x4)0.0f;
#pragma unroll
          for (int t = 0; t < 4; ++t) a2 = mfma16(kf[t], qf[t], a2);
          st[jt] = a2;
        }

        if (kk0 + 63 > wq_abs) {
          int qcol = wq_abs + l16;
#pragma unroll
          for (int jt = 0; jt < 4; ++jt)
#pragma unroll
            for (int r = 0; r < 4; ++r) {
              int key = kk0 + jt * 16 + quad * 4 + r;
              if (key > qcol) st[jt][r] = NEG_SENTINEL;
            }
        }

        float mx = NEG_SENTINEL;
#pragma unroll
        for (int jt = 0; jt < 4; ++jt)
#pragma unroll
          for (int r = 0; r < 4; ++r) mx = fmaxf(mx, st[jt][r]);
        mx = fmaxf(mx, __shfl_xor(mx, 16, 64));
        mx = fmaxf(mx, __shfl_xor(mx, 32, 64));
        float m_new = fmaxf(m_col, mx);
        float alpha = exp2f(m_col - m_new);
        float ts = 0.0f;
#pragma unroll
        for (int jt = 0; jt < 4; ++jt) {
          bf16x4 pk;
#pragma unroll
          for (int r = 0; r < 4; ++r) {
            float p = exp2f(st[jt][r] - m_new);
            ts += p;
            pk[r] = (bf16)p;
          }
          *(bf16x4*)(sP + (wq + l16) * SPS + jt * 16 + quad * 4) = pk;
        }
        ts += __shfl_xor(ts, 16, 64);
        ts += __shfl_xor(ts, 32, 64);
        l_col = l_col * alpha + ts;
        m_col = m_new;
#pragma unroll
        for (int r = 0; r < 4; ++r) {
          float av = __shfl(alpha, quad * 4 + r, 64);
#pragma unroll
          for (int jd = 0; jd < 8; ++jd) o_acc[jd][r] *= av;
        }

#pragma unroll
        for (int ks = 0; ks < 2; ++ks) {
          bf16x8 pf = *(const bf16x8*)(sP + (wq + l16) * SPS + ks * 32 + quad * 8);
#pragma unroll
          for (int jd = 0; jd < 8; ++jd) {
            int pos = (ks * 4 + quad) ^ (l16 & 7);
            bf16x8 vf = *(const bf16x8*)(sVT + (jd * 16 + l16) * ABK + pos * 8);
            o_acc[jd] = mfma16(pf, vf, o_acc[jd]);
          }
        }
      }
    }

#pragma unroll
    for (int r = 0; r < 4; ++r) {
      float lv = __shfl(l_col, quad * 4 + r, 64);
      float inv_l = 1.0f / lv;
      int row = wq_abs + quad * 4 + r;
#pragma unroll
      for (int jd = 0; jd < 8; ++jd) {
        int colo = jd * 16 + l16;
        Oh[(size_t)row * D_ + colo] = (bf16)(o_acc[jd][r] * inv_l);
      }
    }
  }
}

// ---------------------------------------------------------------------------
extern "C" void kernel_launch(void* const* d_in, const int* in_sizes, int n_in,
                              void* d_out, int out_size, void* d_ws, size_t ws_size,
                              hipStream_t stream) {
  const float* x    = (const float*)d_in[0];
  const float* Wq   = (const float*)d_in[1];
  const float* Wk   = (const float*)d_in[2];
  const float* Wv   = (const float*)d_in[3];
  const float* Wo   = (const float*)d_in[4];
  const float* cosT = (const float*)d_in[5];
  const float* sinT = (const float*)d_in[6];
  float* out = (float*)d_out;

  const size_t NE = (size_t)B_ * S_ * D_;   // 8,388,608
  const size_t WE = (size_t)D_ * D_;        // 4,194,304
  const int M = B_ * S_;
  const int cvtX = (int)(NE / 1024);
  const int cvtW = (int)(WE / 1024);

  static bool attr_done = false;
  if (!attr_done) {
    (void)hipFuncSetAttribute(reinterpret_cast<const void*>(gemm_8ph),
                              hipFuncAttributeMaxDynamicSharedMemorySize, QLDS);
    attr_done = true;
  }

  if (ws_size >= (size_t)92274688) {
    // ---- fused-QKV path (88 MB): QKV(48) | xb(16) | Wqkv->ctx+Wo_b(24) ----
    bf16* QKV   = (bf16*)d_ws;              // (4096, 6144) row-major
    bf16* xb    = QKV + (size_t)M * 6144;
    bf16* Wqkv  = xb + NE;
    bf16* ctx   = Wqkv;                     // reuse after QKV GEMM
    bf16* Wob   = Wqkv + 2 * WE;
    bf16* Vt    = xb;                       // reuse after QKV GEMM

    cvt_f32_bf16<<<cvtX, 256, 0, stream>>>(x, xb);
    cvt_f32_bf16<<<cvtW, 256, 0, stream>>>(Wq, Wqkv);
    cvt_f32_bf16<<<cvtW, 256, 0, stream>>>(Wk, Wqkv + WE);
    cvt_f32_bf16<<<cvtW, 256, 0, stream>>>(Wv, Wqkv + 2 * WE);
    // QKV GEMM: M=4096, N=6144 -> grid 24*16 = 384 blocks (256^2 tiles)
    gemm_8ph<<<384, 512, QLDS, stream>>>(xb, Wqkv, QKV, M, 3 * D_, D_, 3 * D_, 16);
    rope_qk<<<(B_ * S_ * H_ * 64) / 256, 256, 0, stream>>>(QKV, QKV + D_, cosT, sinT, 3 * D_);
    transpose_v<<<dim3(32, 2, 32), 256, 0, stream>>>(QKV + 2 * D_, Vt, 3 * D_);
    attn_fwd<<<512, 256, 0, stream>>>(QKV, QKV + D_, Vt, ctx, 3 * D_);
    cvt_f32_bf16<<<cvtW, 256, 0, stream>>>(Wo, Wob);
    // out GEMM: legacy 128^2 (grid 16x32 = 512 = 2 balanced rounds)
    gemm_xwt<float><<<dim3(16, 32), 256, 0, stream>>>(ctx, Wob, out, M, D_, D_, D_);
  } else {
    // ---- fallback (72 MB): separate GEMMs, legacy kernel ----
    bf16* Qb    = (bf16*)d_ws;
    bf16* Kb    = Qb + NE;
    bf16* Vb    = Kb + NE;
    bf16* Cb    = Vb + NE;                  // bf16(x) -> later Vt
    bf16* Wslot = Cb + NE;

    cvt_f32_bf16<<<cvtX, 256, 0, stream>>>(x, Cb);
    cvt_f32_bf16<<<cvtW, 256, 0, stream>>>(Wq, Wslot);
    gemm_xwt<bf16><<<dim3(16, 32), 256, 0, stream>>>(Cb, Wslot, Qb, M, D_, D_, D_);
    cvt_f32_bf16<<<cvtW, 256, 0, stream>>>(Wk, Wslot);
    gemm_xwt<bf16><<<dim3(16, 32), 256, 0, stream>>>(Cb, Wslot, Kb, M, D_, D_, D_);
    cvt_f32_bf16<<<cvtW, 256, 0, stream>>>(Wv, Wslot);
    gemm_xwt<bf16><<<dim3(16, 32), 256, 0, stream>>>(Cb, Wslot, Vb, M, D_, D_, D_);
    rope_qk<<<(B_ * S_ * H_ * 64) / 256, 256, 0, stream>>>(Qb, Kb, cosT, sinT, D_);
    transpose_v<<<dim3(32, 2, 32), 256, 0, stream>>>(Vb, Cb, D_);
    attn_fwd<<<512, 256, 0, stream>>>(Qb, Kb, Cb, Vb, D_);
    cvt_f32_bf16<<<cvtW, 256, 0, stream>>>(Wo, Wslot);
    gemm_xwt<float><<<dim3(16, 32), 256, 0, stream>>>(Vb, Wslot, out, M, D_, D_, D_);
  }
}